// Round 4
// baseline (535.039 us; speedup 1.0000x reference)
//
#include <hip/hip_runtime.h>

#define T_     24
#define LAMDA_ 0.2f

// output layout (flat f32): outs[24,64,256] | cs[64,256] | las[24,64,32] | gas[24,64,256]
#define OFF_CS  393216
#define OFF_LAS 409600
#define OFF_GAS 458752

// lookup tables: 1024 samples over a in [-16,16]
#define TBL_N   1024
#define TBL_H   (32.0f/1023.0f)
#define TBL_IH  (1023.0f/32.0f)

__device__ __forceinline__ float clamp15(float x){ return fminf(15.f, fmaxf(-15.f, x)); }
__device__ __forceinline__ float rcp_(float x){ return __builtin_amdgcn_rcpf(x); }

// ---------------------------------------------------------------------------
// R13: R12 steady 420us, spill-free (WRITE 3.3MB), bank-conf 0. Phase D
// (pair-rational, ~410 VALU + 72 rcp/thread) replaced by per-step scalar
// lookup tables: s_g[s] = sum_o G(hf_g[o,s]) with G(a)=sum_d v_d tanh(a+y_d)
// the SAME function for all 6144 evals (and L(a) for s_l). Per step: build
// G,L as 1024-sample tables (24 exp+rcp per thread, distributed); eval via
// 4-point Lagrange cubic whose segment index + weights are CONSTANT over t
// (hf values fixed at init) -> precomputed into registers before the t-loop.
// Phase D: 6x(4 ds_read + 4 fma) + one 4-pt dot. Phase C: no exp/pairs, just
// writes (2y, v). Eg/El LDS deleted. +1 barrier/step (build). Lagrange err
// ~3e-5 per eval << 2e-3 scale; inf-safe (exp->inf => rcp->0 => tanh=+-1).
// Tripwire: WRITE_SIZE must stay ~3.3MB (spill watch, always-live +35 regs).
// ---------------------------------------------------------------------------
__global__ __launch_bounds__(1024, 4) void spat_kernel(
    const float* __restrict__ li,  const float* __restrict__ gi,
    const float* __restrict__ ls,  const float* __restrict__ gs,
    const float* __restrict__ dist,
    const float* __restrict__ la0, const float* __restrict__ ga0,
    const float* __restrict__ Wcl, const float* __restrict__ bcl,
    const float* __restrict__ Wll, const float* __restrict__ bll, const float* __restrict__ vl,
    const float* __restrict__ Wcg, const float* __restrict__ bcg,
    const float* __restrict__ Wlg, const float* __restrict__ blg, const float* __restrict__ vg,
    const float* __restrict__ Wih, const float* __restrict__ bih, const float* __restrict__ bhh,
    float* __restrict__ out)
{
    __shared__ float outb[6144];             // h outputs  [t][i]
    __shared__ float gasb[6144];             // gas        [t][s]
    __shared__ float lasb[768];              // las        [t][l]
    __shared__ float csb[256];               // c at t=23
    __shared__ __align__(16) union {
        float wcg[6144];                     // Wcg staging (init only)
        struct {
            float sgred[1024];
            float gbuf[768];
            float xv[288];
            float cq[256];
            float slg[32];
        } p;
    } U;
    __shared__ float gt[TBL_N];              // per-step table G (global branch)
    __shared__ float lt[TBL_N];              // per-step table L (local branch)
    __shared__ __align__(8) float2 ygp[24], ylp[24];   // (2*y_d, v_d) per step
    __shared__ float dstf[256];
    __shared__ float bsum[768];              // bih+bhh for used gate rows
    __shared__ float bcf[48];                // bll|blg
    __shared__ float vlf[24], vgf[24], cbuf[2];

    const int b = blockIdx.x, tid = threadIdx.x;
    const int s = tid & 255, ogrp = tid >> 8;

    // ---- small init (before first barrier) ----
    if (tid < 256) dstf[tid] = dist[b*256 + tid];
    if (tid < 24)  { vlf[tid] = vl[tid]; vgf[tid] = vg[tid]; }
    if (tid < 48)  bcf[tid] = (tid < 24) ? bll[tid] : blg[tid - 24];
    if (tid < 768) {
        const int wrow = tid + ((tid >= 256) ? 256 : 0);
        bsum[tid] = bih[wrow] + bhh[wrow];
    }
    if (tid == 0)  { float s1 = 0.f; for (int d = 0; d < 24; d++) s1 += vl[d]; cbuf[0] = s1; }
    if (tid == 1)  { float s1 = 0.f; for (int d = 0; d < 24; d++) s1 += vg[d]; cbuf[1] = s1; }

    // ---- hf_g: thread (s, ogrp) accumulates 6 o's over c<24, j<32 ----
    float acc[6];
#pragma unroll
    for (int i = 0; i < 6; i++) acc[i] = bcg[ogrp*6 + i];

    for (int hc = 0; hc < 3; hc++) {
        for (int k = tid; k < 6144; k += 1024) {
            const int o = k >> 8, r = k & 255;
            U.wcg[k] = Wcg[o*768 + hc*256 + r];
        }
        __syncthreads();
        for (int cc = 0; cc < 8; cc++) {
            const int c = hc*8 + cc;
            const float4* gp = (const float4*)(gs + ((size_t)b*196608 + c*8192 + s*32));
#pragma unroll
            for (int h = 0; h < 2; h++) {            // two 16-float halves of j
                float gv[16];
#pragma unroll
                for (int m = 0; m < 4; m++) {
                    const float4 g = gp[h*4 + m];
                    gv[4*m] = g.x; gv[4*m+1] = g.y; gv[4*m+2] = g.z; gv[4*m+3] = g.w;
                }
#pragma unroll
                for (int i = 0; i < 6; i++) {
                    const float4* wp = (const float4*)(U.wcg + ((ogrp*6 + i)*256 + cc*32)) + h*4;
                    float a = acc[i];
#pragma unroll
                    for (int m = 0; m < 4; m++) {
                        const float4 w = wp[m];
                        a = fmaf(w.x, gv[4*m],   a);
                        a = fmaf(w.y, gv[4*m+1], a);
                        a = fmaf(w.z, gv[4*m+2], a);
                        a = fmaf(w.w, gv[4*m+3], a);
                    }
                    acc[i] = a;
                }
            }
        }
        __syncthreads();
    }

    const int lg = tid >> 5, ol = tid & 31;    // s_l layout (32 l-groups x 32)

    // ---- hf_l a-value for THIS thread's (l=lg, o=ol) ----
    float al_a = 0.f;
    if (ol < 24) {
        float a = bcl[ol];
        for (int c = 0; c < 24; c++)
            a = fmaf(Wcl[ol*24 + c], ls[b*768 + c*32 + lg], a);
        al_a = a;
    }

    // ---- precompute table-eval positions + Lagrange-cubic weights
    //      (constant over t: hf values never change) ----
    int   mg[6];  float4 wg[6];
    int   mlx;    float4 wlx;
    {
#define MKW(AVAL, MM, WW) { \
        const float t_  = (clamp15(AVAL) + 16.f) * TBL_IH; \
        const float jf_ = floorf(t_); \
        const float f_  = t_ - jf_; \
        MM = (int)jf_ - 1; \
        const float fp_ = f_ + 1.f, fm_ = f_ - 1.f, f2_ = f_ - 2.f; \
        WW.x = -f_*fm_*f2_*(1.f/6.f); \
        WW.y =  fp_*fm_*f2_*0.5f; \
        WW.z = -fp_*f_*f2_*0.5f; \
        WW.w =  fp_*f_*fm_*(1.f/6.f); }
#pragma unroll
        for (int i = 0; i < 6; i++) MKW(acc[i], mg[i], wg[i])
        MKW(al_a, mlx, wlx)
#undef MKW
    }

    // ---- x for t=0 (wcg union dead after hc-loop barrier) ----
    if (tid < 288) {
        if (tid < 32) U.p.xv[tid] = la0[b*32 + tid] * li[b*32 + tid];
        else { const int ss = tid - 32; U.p.xv[tid] = ga0[b*256 + ss] * gi[b*256 + ss]; }
    }
    __syncthreads();

    const int u8 = tid & 7, slot = tid >> 3;   // phase A/C team layout
    const int rbase = slot*6;                  // 6 contiguous rows per slot

    for (int t = 0; t < T_; t++) {
        // prefetch next-step inputs for the fused x-build (wave0: li, wave1: gi)
        float liN = 0.f;
        float giN0 = 0.f, giN1 = 0.f, giN2 = 0.f, giN3 = 0.f;
        if (t < T_ - 1) {
            if (tid < 32) liN = li[(t+1)*2048 + b*32 + tid];
            else if (tid >= 64 && tid < 128) {
                const int lane = tid - 64;
                giN0 = gi[(t+1)*16384 + b*256 + lane];
                giN1 = gi[(t+1)*16384 + b*256 + lane + 64];
                giN2 = gi[(t+1)*16384 + b*256 + lane + 128];
                giN3 = gi[(t+1)*16384 + b*256 + lane + 192];
            }
        }

        // ---- A: gates GEMV, 8 lanes/row, named accumulators, 2 fence
        //      groups of 3 rows (9 loads in flight) ----
        {
            const float4* xp = (const float4*)U.p.xv;
            float ar0 = 0.f, ar1 = 0.f, ar2 = 0.f, ar3 = 0.f, ar4 = 0.f, ar5 = 0.f;
#pragma unroll 1
            for (int jc = 0; jc < 3; jc++) {
                const float4 x0 = xp[jc*24 + u8];
                const float4 x1 = xp[jc*24 + 8 + u8];
                const float4 x2 = xp[jc*24 + 16 + u8];

#define KROW(kk, AR) { \
                const int row_ = rbase + (kk); \
                const int wrow_ = row_ + ((row_ >= 256) ? 256 : 0); \
                const float4* wp_ = (const float4*)(Wih + wrow_*288) + jc*24 + u8; \
                const float4 w0_ = wp_[0], w1_ = wp_[8], w2_ = wp_[16]; \
                float a_ = AR; \
                a_ = fmaf(w0_.x,x0.x,a_); a_ = fmaf(w0_.y,x0.y,a_); \
                a_ = fmaf(w0_.z,x0.z,a_); a_ = fmaf(w0_.w,x0.w,a_); \
                a_ = fmaf(w1_.x,x1.x,a_); a_ = fmaf(w1_.y,x1.y,a_); \
                a_ = fmaf(w1_.z,x1.z,a_); a_ = fmaf(w1_.w,x1.w,a_); \
                a_ = fmaf(w2_.x,x2.x,a_); a_ = fmaf(w2_.y,x2.y,a_); \
                a_ = fmaf(w2_.z,x2.z,a_); a_ = fmaf(w2_.w,x2.w,a_); \
                AR = a_; }

                KROW(0, ar0) KROW(1, ar1) KROW(2, ar2)
                __builtin_amdgcn_sched_barrier(0);
                KROW(3, ar3) KROW(4, ar4) KROW(5, ar5)
                __builtin_amdgcn_sched_barrier(0);
#undef KROW
            }
            {
                float a_;
#define RED(kk, AR) { a_ = AR; \
                a_ += __shfl_xor(a_, 1); a_ += __shfl_xor(a_, 2); a_ += __shfl_xor(a_, 4); \
                if (u8 == 0) { const int row_ = rbase + (kk); U.p.gbuf[row_] = a_ + bsum[row_]; } }
                RED(0, ar0) RED(1, ar1) RED(2, ar2) RED(3, ar3) RED(4, ar4) RED(5, ar5)
#undef RED
            }
        }
        __syncthreads();

        // ---- B: c = sig(i)*tanh(g); h = sig(o)*tanh(c); h,c -> LDS only ----
        if (tid < 256) {
            const float ig = U.p.gbuf[tid], gg = U.p.gbuf[256 + tid], ot = U.p.gbuf[512 + tid];
            const float sig_i = rcp_(1.f + __expf(-ig));
            const float th_g  = 1.f - 2.f*rcp_(1.f + __expf(2.f*clamp15(gg)));
            const float c     = sig_i * th_g;
            const float sig_o = rcp_(1.f + __expf(-ot));
            const float th_c  = 1.f - 2.f*rcp_(1.f + __expf(2.f*c));
            const float h     = sig_o * th_c;
            U.p.cq[tid] = c;
            outb[t*256 + tid] = h;
            if (t == T_ - 1) csb[tid] = c;
        }
        __syncthreads();

        // ---- C: 48 dots x 8-lane teams; write (2y, v) pairs ----
        if (tid < 384) {
            const int dot = slot;            // tid>>3 < 48
            const float* Wr = (dot < 24) ? (Wll + dot*256) : (Wlg + (dot - 24)*256);
            const float4* wp = (const float4*)Wr;
            const float4* cp = (const float4*)U.p.cq;
            float a0 = 0.f, a1 = 0.f;
#pragma unroll
            for (int j = 0; j < 8; j += 2) {
                const float4 w0 = wp[j*8 + u8],     c0 = cp[j*8 + u8];
                const float4 w1 = wp[(j+1)*8 + u8], c1 = cp[(j+1)*8 + u8];
                a0 = fmaf(w0.x,c0.x,a0); a0 = fmaf(w0.y,c0.y,a0);
                a0 = fmaf(w0.z,c0.z,a0); a0 = fmaf(w0.w,c0.w,a0);
                a1 = fmaf(w1.x,c1.x,a1); a1 = fmaf(w1.y,c1.y,a1);
                a1 = fmaf(w1.z,c1.z,a1); a1 = fmaf(w1.w,c1.w,a1);
            }
            float a = a0 + a1;
            a += __shfl_xor(a, 1); a += __shfl_xor(a, 2); a += __shfl_xor(a, 4);
            if (u8 == 0) {
                const float y = a + bcf[dot];
                if (dot < 24) ylp[dot]      = make_float2(2.f*y, vlf[dot]);
                else          ygp[dot - 24] = make_float2(2.f*y, vgf[dot - 24]);
            }
        }
        __syncthreads();

        // ---- build: per-step tables G,L (one knot per thread each) ----
        {
            const float ak2 = 2.f*(-16.f + (float)tid * TBL_H);
            float sg_ = 0.f, sl_ = 0.f;
#pragma unroll 4
            for (int d = 0; d < 24; d++) {
                const float2 pg = ygp[d];
                const float2 pl = ylp[d];
                sg_ = fmaf(pg.y, rcp_(1.f + __expf(ak2 + pg.x)), sg_);
                sl_ = fmaf(pl.y, rcp_(1.f + __expf(ak2 + pl.x)), sl_);
            }
            gt[tid] = cbuf[1] - 2.f*sg_;
            lt[tid] = cbuf[0] - 2.f*sl_;
        }
        __syncthreads();

        // ---- D: s_g = 6 table evals; s_l = 1 eval + shfl reduce ----
        {
            float a0 = 0.f;
#pragma unroll
            for (int i = 0; i < 6; i++) {
                const float* p_ = gt + mg[i];
                float v_ = wg[i].x * p_[0];
                v_ = fmaf(wg[i].y, p_[1], v_);
                v_ = fmaf(wg[i].z, p_[2], v_);
                v_ = fmaf(wg[i].w, p_[3], v_);
                a0 += v_;
            }
            U.p.sgred[tid] = a0;
        }
        {
            float bsl = 0.f;
            if (ol < 24) {
                const float* p_ = lt + mlx;
                bsl = wlx.x * p_[0];
                bsl = fmaf(wlx.y, p_[1], bsl);
                bsl = fmaf(wlx.z, p_[2], bsl);
                bsl = fmaf(wlx.w, p_[3], bsl);
            }
            bsl += __shfl_xor(bsl, 1);  bsl += __shfl_xor(bsl, 2);
            bsl += __shfl_xor(bsl, 4);  bsl += __shfl_xor(bsl, 8);
            bsl += __shfl_xor(bsl, 16);
            if (ol == 0) U.p.slg[lg] = bsl;
        }
        __syncthreads();

        // ---- E: both softmaxes + next-step x-build (LDS outputs) ----
        if (tid < 32) {                       // wave0: s_l softmax
            const float sv = U.p.slg[tid];
            float m = sv;
#pragma unroll
            for (int mk = 16; mk >= 1; mk >>= 1) m = fmaxf(m, __shfl_xor(m, mk));
            const float e = __expf(sv - m);
            float ss = e;
#pragma unroll
            for (int mk = 16; mk >= 1; mk >>= 1) ss += __shfl_xor(ss, mk);
            const float r = e * rcp_(ss);
            lasb[t*32 + tid] = r;
            if (t < T_ - 1) U.p.xv[tid] = r * liN;
        } else if (tid >= 64 && tid < 128) {  // wave1: s_g softmax, 4 s/lane
            const int lane = tid - 64;
            float vv0, vv1, vv2, vv3;
            {
                const float t0 = U.p.sgred[lane]     + U.p.sgred[256+lane]     + U.p.sgred[512+lane]     + U.p.sgred[768+lane];
                const float t1 = U.p.sgred[lane+64]  + U.p.sgred[256+lane+64]  + U.p.sgred[512+lane+64]  + U.p.sgred[768+lane+64];
                const float t2 = U.p.sgred[lane+128] + U.p.sgred[256+lane+128] + U.p.sgred[512+lane+128] + U.p.sgred[768+lane+128];
                const float t3 = U.p.sgred[lane+192] + U.p.sgred[256+lane+192] + U.p.sgred[512+lane+192] + U.p.sgred[768+lane+192];
                vv0 = (1.f-LAMDA_)*t0 + LAMDA_*dstf[lane];
                vv1 = (1.f-LAMDA_)*t1 + LAMDA_*dstf[lane+64];
                vv2 = (1.f-LAMDA_)*t2 + LAMDA_*dstf[lane+128];
                vv3 = (1.f-LAMDA_)*t3 + LAMDA_*dstf[lane+192];
            }
            float m = fmaxf(fmaxf(vv0, vv1), fmaxf(vv2, vv3));
#pragma unroll
            for (int mk = 32; mk >= 1; mk >>= 1) m = fmaxf(m, __shfl_xor(m, mk));
            const float e0 = __expf(vv0 - m), e1 = __expf(vv1 - m);
            const float e2 = __expf(vv2 - m), e3 = __expf(vv3 - m);
            float ss = (e0 + e1) + (e2 + e3);
#pragma unroll
            for (int mk = 32; mk >= 1; mk >>= 1) ss += __shfl_xor(ss, mk);
            const float inv = rcp_(ss);
            const float r0 = e0*inv, r1 = e1*inv, r2 = e2*inv, r3 = e3*inv;
            float* gb = gasb + t*256;
            gb[lane] = r0; gb[lane+64] = r1; gb[lane+128] = r2; gb[lane+192] = r3;
            if (t < T_ - 1) {
                U.p.xv[32+lane]     = r0 * giN0;
                U.p.xv[32+lane+64]  = r1 * giN1;
                U.p.xv[32+lane+128] = r2 * giN2;
                U.p.xv[32+lane+192] = r3 * giN3;
            }
        }
        __syncthreads();
    }

    // ---- final flush: LDS output buffers -> global, coalesced ----
    for (int k = tid; k < 6144; k += 1024) {
        const int tt = k >> 8, ii = k & 255;
        out[tt*16384 + b*256 + ii]           = outb[k];
        out[OFF_GAS + tt*16384 + b*256 + ii] = gasb[k];
    }
    if (tid < 768) out[OFF_LAS + (tid >> 5)*2048 + b*32 + (tid & 31)] = lasb[tid];
    if (tid < 256) out[OFF_CS + b*256 + tid] = csb[tid];
}

extern "C" void kernel_launch(void* const* d_in, const int* in_sizes, int n_in,
                              void* d_out, int out_size, void* d_ws, size_t ws_size,
                              hipStream_t stream)
{
    const float* li   = (const float*)d_in[0];
    const float* gi   = (const float*)d_in[1];
    const float* ls   = (const float*)d_in[2];
    const float* gs   = (const float*)d_in[3];
    const float* dist = (const float*)d_in[4];
    const float* la0  = (const float*)d_in[5];
    const float* ga0  = (const float*)d_in[6];
    const float* Wcl  = (const float*)d_in[7];
    const float* bcl  = (const float*)d_in[8];
    const float* Wll  = (const float*)d_in[9];
    const float* bll  = (const float*)d_in[10];
    const float* vl   = (const float*)d_in[11];
    const float* Wcg  = (const float*)d_in[12];
    const float* bcg  = (const float*)d_in[13];
    const float* Wlg  = (const float*)d_in[14];
    const float* blg  = (const float*)d_in[15];
    const float* vg   = (const float*)d_in[16];
    const float* Wih  = (const float*)d_in[17];
    const float* bih  = (const float*)d_in[18];
    const float* bhh  = (const float*)d_in[19];

    spat_kernel<<<64, 1024, 0, stream>>>(li, gi, ls, gs, dist, la0, ga0,
                                         Wcl, bcl, Wll, bll, vl,
                                         Wcg, bcg, Wlg, blg, vg,
                                         Wih, bih, bhh, (float*)d_out);
}